// Round 3
// baseline (673.837 us; speedup 1.0000x reference)
//
#include <hip/hip_runtime.h>
#include <hip/hip_bf16.h>
#include <cstdint>
#include <cstddef>

typedef __bf16 bf16_t;
typedef __bf16 bf16x8 __attribute__((ext_vector_type(8)));
typedef __bf16 bf16x4 __attribute__((ext_vector_type(4)));
typedef float f32x4 __attribute__((ext_vector_type(4)));

#define MFMA16(a, b, c) __builtin_amdgcn_mfma_f32_16x16x32_bf16((a), (b), (c), 0, 0, 0)

// Load 8 contiguous elements starting at element index `idx`, as bf16x8.
template <bool F32>
__device__ __forceinline__ bf16x8 ld8(const void* base, size_t idx) {
    if constexpr (F32) {
        const float* p = (const float*)base + idx;
        f32x4 a = *reinterpret_cast<const f32x4*>(p);
        f32x4 b = *reinterpret_cast<const f32x4*>(p + 4);
        bf16x8 r;
        r[0] = (bf16_t)a[0]; r[1] = (bf16_t)a[1]; r[2] = (bf16_t)a[2]; r[3] = (bf16_t)a[3];
        r[4] = (bf16_t)b[0]; r[5] = (bf16_t)b[1]; r[6] = (bf16_t)b[2]; r[7] = (bf16_t)b[3];
        return r;
    } else {
        return *reinterpret_cast<const bf16x8*>((const bf16_t*)base + idx);
    }
}

template <bool F32>
__device__ __forceinline__ float ld1(const void* base, int i) {
    if constexpr (F32) return ((const float*)base)[i];
    else return (float)((const bf16_t*)base)[i];
}

// Detect input dtype from ln_g (== ones). f32 1.0 -> 0x3F800000; bf16 ones -> 0x3F803F80.
__global__ void k_detect(const void* lng, int* flag) {
    if (threadIdx.x == 0) {
        unsigned int w = *(const unsigned int*)lng;
        *flag = (w == 0x3F800000u) ? 1 : 0;
    }
}

// ---------------------------------------------------------------------------
// K1: fused weight precompute -> bf16 WH/WZ in ws.
//  WH[d,d1]      = RS * sum_e Wq[e,d]        * Whk[e,d1]
//  WH[512+o,d1]  =      sum_e Wout[o,e]      * Whv[e,d1]
//  WZ[d,d1]      = RS * sum_e Wq[1024+e,d]   * Wzk[e,d1]
//  WZ[512+o,d1]  =      sum_e Wout[o,1024+e] * Wzv[e,d1]
// ---------------------------------------------------------------------------
template <bool F32>
__global__ __launch_bounds__(256) void k_fusew(
    const void* __restrict__ Whk, const void* __restrict__ Whv,
    const void* __restrict__ Wzk, const void* __restrict__ Wzv,
    const void* __restrict__ Wq,  const void* __restrict__ Wout,
    bf16_t* __restrict__ WH, bf16_t* __restrict__ WZ,
    const int* __restrict__ flag)
{
    if ((*flag != 0) != F32) return;
    __shared__ bf16_t LA[64][40];
    __shared__ bf16_t LB[64][40];
    const int tid = threadIdx.x;
    const int lane = tid & 63, wid = tid >> 6;
    const int L15 = lane & 15, qd = lane >> 4;
    const int quad = blockIdx.x & 3, tile = blockIdx.x >> 2;
    const int ti = (tile >> 3) * 64, tj = (tile & 7) * 64;
    const float RS = 0.04419417382415922f;  // 1/sqrt(512)

    const void* Lp; size_t Loff; const void* Rp; bf16_t* Op;
    int orow; float scale; int transL;
    switch (quad) {
        case 0:  Lp = Wq;   Loff = 0;      Rp = Whk; Op = WH; orow = 0;   scale = RS;  transL = 1; break;
        case 1:  Lp = Wout; Loff = 0;      Rp = Whv; Op = WH; orow = 512; scale = 1.f; transL = 0; break;
        case 2:  Lp = Wq;   Loff = 524288; Rp = Wzk; Op = WZ; orow = 0;   scale = RS;  transL = 1; break;
        default: Lp = Wout; Loff = 1024;   Rp = Wzv; Op = WZ; orow = 512; scale = 1.f; transL = 0; break;
    }

    f32x4 acc[4];
#pragma unroll
    for (int t = 0; t < 4; t++) acc[t] = (f32x4){0.f, 0.f, 0.f, 0.f};

    for (int kc = 0; kc < 32; kc++) {
        const int k0 = kc * 32;
        __syncthreads();
        if (transL) {
            int k = tid >> 3, i0 = (tid & 7) * 8;
            bf16x8 v = ld8<F32>(Lp, Loff + (size_t)(k0 + k) * 512 + ti + i0);
#pragma unroll
            for (int u = 0; u < 8; u++) LA[i0 + u][k] = v[u];
        } else {
            int i = tid >> 2, kk0 = (tid & 3) * 8;
            bf16x8 v = ld8<F32>(Lp, Loff + (size_t)(ti + i) * 2048 + k0 + kk0);
            *reinterpret_cast<bf16x8*>(&LA[i][kk0]) = v;
        }
        {
            int k = tid >> 3, j0 = (tid & 7) * 8;
            bf16x8 v = ld8<F32>(Rp, (size_t)(k0 + k) * 512 + tj + j0);
#pragma unroll
            for (int u = 0; u < 8; u++) LB[j0 + u][k] = v[u];
        }
        __syncthreads();
        bf16x8 af = *reinterpret_cast<bf16x8*>(&LA[wid * 16 + L15][qd * 8]);
#pragma unroll
        for (int t = 0; t < 4; t++) {
            bf16x8 bfr = *reinterpret_cast<bf16x8*>(&LB[t * 16 + L15][qd * 8]);
            acc[t] = MFMA16(af, bfr, acc[t]);
        }
    }
#pragma unroll
    for (int t = 0; t < 4; t++) {
        int col = tj + t * 16 + L15;
#pragma unroll
        for (int r = 0; r < 4; r++) {
            int row = ti + wid * 16 + qd * 4 + r;
            Op[(size_t)(orow + row) * 512 + col] = (bf16_t)(acc[t][r] * scale);
        }
    }
}

// ---------------------------------------------------------------------------
// K2: fused per-batch pipeline. One block per batch n, 16 waves.
// G[k,d] = sum_d1 h[k,d1] WH[d,d1] + z[k,d1] WZ[d,d1]       (d in [0,512))
// logits[k,q] = sum_d G[k,d] h[q,d];  P = softmax_q(logits)
// VV[q,d] = sum_d1 h[q,d1] WH[512+d,d1] + z[q,d1] WZ[512+d,d1]
// out[k,d] = LN_d( sum_q P[k,q] VV[q,d] )
// ---------------------------------------------------------------------------
template <bool F32>
__global__ __launch_bounds__(1024) void k_batch(
    const void* __restrict__ H, const void* __restrict__ Z,
    const bf16_t* __restrict__ WH, const bf16_t* __restrict__ WZ,
    const void* __restrict__ lng, const void* __restrict__ lnb,
    void* __restrict__ out, const int* __restrict__ flag)
{
    if ((*flag != 0) != F32) return;
    __shared__ __align__(16) char lds_raw[48128];
    bf16_t* lds_bf = (bf16_t*)lds_raw;
    float*  lds_f  = (float*)lds_raw;
    bf16_t* Gbuf = lds_bf;           // [64][264]   (region0)
    float*  Sl   = lds_f;            // [64][64]    (region0)
    bf16_t* VT   = lds_bf;           // [256][72]   (region0)
    bf16_t* Sp   = lds_bf + 18432;   // [64][72]
    float*  Rs   = lds_f + 11520;    // [4][64]
    float*  Rq   = lds_f + 11776;    // [4][64]

    const int n = blockIdx.x;
    const int tid = threadIdx.x, lane = tid & 63, w = tid >> 6;
    const int L15 = lane & 15, qd = lane >> 4;
    const int strip = w & 3, grp = w >> 2;
    const size_t hoff = (size_t)n * 32768;

    f32x4 a1 = (f32x4){0.f, 0.f, 0.f, 0.f};  // logits tile (strip, grp)

    // ============ G + logits, two d-halves of 256 ============
    for (int hf = 0; hf < 2; hf++) {
        f32x4 ga[4];
#pragma unroll
        for (int mt = 0; mt < 4; mt++) ga[mt] = (f32x4){0.f, 0.f, 0.f, 0.f};
        const bf16_t* wh = WH + (size_t)(hf * 256 + w * 16 + L15) * 512;
        const bf16_t* wz = WZ + (size_t)(hf * 256 + w * 16 + L15) * 512;
#pragma unroll 4
        for (int kc = 0; kc < 16; kc++) {
            const int ko = kc * 32 + qd * 8;
            bf16x8 bh = *reinterpret_cast<const bf16x8*>(wh + ko);
            bf16x8 bz = *reinterpret_cast<const bf16x8*>(wz + ko);
#pragma unroll
            for (int mt = 0; mt < 4; mt++) {
                bf16x8 ah = ld8<F32>(H, hoff + (size_t)(mt * 16 + L15) * 512 + ko);
                bf16x8 az = ld8<F32>(Z, hoff + (size_t)(mt * 16 + L15) * 512 + ko);
                ga[mt] = MFMA16(ah, bh, ga[mt]);
                ga[mt] = MFMA16(az, bz, ga[mt]);
            }
        }
        __syncthreads();  // prior readers of region0 done
#pragma unroll
        for (int mt = 0; mt < 4; mt++)
#pragma unroll
            for (int r = 0; r < 4; r++)
                Gbuf[(size_t)(mt * 16 + qd * 4 + r) * 264 + w * 16 + L15] =
                    (bf16_t)ga[mt][r];
        __syncthreads();
        // logits partial over this d-half
#pragma unroll
        for (int kcf = 0; kcf < 8; kcf++) {
            bf16x8 af = *reinterpret_cast<bf16x8*>(
                &Gbuf[(size_t)(strip * 16 + L15) * 264 + kcf * 32 + qd * 8]);
            bf16x8 bq = ld8<F32>(H, hoff + (size_t)(grp * 16 + L15) * 512 +
                                         hf * 256 + kcf * 32 + qd * 8);
            a1 = MFMA16(af, bq, a1);
        }
    }
    __syncthreads();
#pragma unroll
    for (int r = 0; r < 4; r++)
        Sl[(size_t)(strip * 16 + qd * 4 + r) * 64 + grp * 16 + L15] = a1[r];
    __syncthreads();

    // ============ softmax over q (dim -1) ============
    {
        int row = tid >> 4, c0 = (tid & 15) * 4;
        float4 v = *reinterpret_cast<float4*>(&Sl[(size_t)row * 64 + c0]);
        float mx = fmaxf(fmaxf(v.x, v.y), fmaxf(v.z, v.w));
#pragma unroll
        for (int m = 1; m < 16; m <<= 1) mx = fmaxf(mx, __shfl_xor(mx, m));
        float e0 = __expf(v.x - mx), e1 = __expf(v.y - mx);
        float e2 = __expf(v.z - mx), e3 = __expf(v.w - mx);
        float s = e0 + e1 + e2 + e3;
#pragma unroll
        for (int m = 1; m < 16; m <<= 1) s += __shfl_xor(s, m);
        float inv = 1.0f / s;
        bf16x4 p;
        p[0] = (bf16_t)(e0 * inv); p[1] = (bf16_t)(e1 * inv);
        p[2] = (bf16_t)(e2 * inv); p[3] = (bf16_t)(e3 * inv);
        *reinterpret_cast<bf16x4*>(&Sp[(size_t)row * 72 + c0]) = p;
    }
    __syncthreads();

    // ============ VV + P·V, two d-halves of 256 ============
    f32x4 acc[8];
#pragma unroll
    for (int j = 0; j < 8; j++) acc[j] = (f32x4){0.f, 0.f, 0.f, 0.f};

    for (int hf2 = 0; hf2 < 2; hf2++) {
        f32x4 va[4];
#pragma unroll
        for (int mt = 0; mt < 4; mt++) va[mt] = (f32x4){0.f, 0.f, 0.f, 0.f};
        const bf16_t* wh = WH + (size_t)(512 + hf2 * 256 + w * 16 + L15) * 512;
        const bf16_t* wz = WZ + (size_t)(512 + hf2 * 256 + w * 16 + L15) * 512;
#pragma unroll 4
        for (int kc = 0; kc < 16; kc++) {
            const int ko = kc * 32 + qd * 8;
            bf16x8 bh = *reinterpret_cast<const bf16x8*>(wh + ko);
            bf16x8 bz = *reinterpret_cast<const bf16x8*>(wz + ko);
#pragma unroll
            for (int mt = 0; mt < 4; mt++) {
                bf16x8 ah = ld8<F32>(H, hoff + (size_t)(mt * 16 + L15) * 512 + ko);
                bf16x8 az = ld8<F32>(Z, hoff + (size_t)(mt * 16 + L15) * 512 + ko);
                va[mt] = MFMA16(ah, bh, va[mt]);
                va[mt] = MFMA16(az, bz, va[mt]);
            }
        }
#pragma unroll
        for (int mt = 0; mt < 4; mt++) {
            bf16x4 pk;
#pragma unroll
            for (int r = 0; r < 4; r++) pk[r] = (bf16_t)va[mt][r];
            *reinterpret_cast<bf16x4*>(
                &VT[(size_t)(w * 16 + L15) * 72 + mt * 16 + qd * 4]) = pk;
        }
        __syncthreads();
#pragma unroll
        for (int kcq = 0; kcq < 2; kcq++) {
            bf16x8 ap = *reinterpret_cast<bf16x8*>(
                &Sp[(size_t)(strip * 16 + L15) * 72 + kcq * 32 + qd * 8]);
#pragma unroll
            for (int dt = 0; dt < 4; dt++) {
                bf16x8 bv = *reinterpret_cast<bf16x8*>(
                    &VT[(size_t)(grp * 64 + dt * 16 + L15) * 72 + kcq * 32 + qd * 8]);
                acc[hf2 * 4 + dt] = MFMA16(ap, bv, acc[hf2 * 4 + dt]);
            }
        }
        __syncthreads();
    }

    // ============ LayerNorm over d (512) ============
    float s4[4] = {0.f, 0.f, 0.f, 0.f}, ss4[4] = {0.f, 0.f, 0.f, 0.f};
#pragma unroll
    for (int j = 0; j < 8; j++)
#pragma unroll
        for (int r = 0; r < 4; r++) { float x = acc[j][r]; s4[r] += x; ss4[r] += x * x; }
#pragma unroll
    for (int m = 1; m < 16; m <<= 1)
#pragma unroll
        for (int r = 0; r < 4; r++) {
            s4[r]  += __shfl_xor(s4[r], m);
            ss4[r] += __shfl_xor(ss4[r], m);
        }
    if (L15 == 0)
#pragma unroll
        for (int r = 0; r < 4; r++) {
            int row = strip * 16 + qd * 4 + r;
            Rs[grp * 64 + row] = s4[r];
            Rq[grp * 64 + row] = ss4[r];
        }
    __syncthreads();
    float mean[4], rstd[4];
#pragma unroll
    for (int r = 0; r < 4; r++) {
        int row = strip * 16 + qd * 4 + r;
        float S = Rs[row] + Rs[64 + row] + Rs[128 + row] + Rs[192 + row];
        float Q = Rq[row] + Rq[64 + row] + Rq[128 + row] + Rq[192 + row];
        float mu = S * (1.f / 512.f);
        float var = Q * (1.f / 512.f) - mu * mu;
        mean[r] = mu;
        rstd[r] = rsqrtf(var + 1e-5f);
    }
#pragma unroll
    for (int j = 0; j < 8; j++) {
        int col = (j >> 2) * 256 + grp * 64 + (j & 3) * 16 + L15;
        float gg = ld1<F32>(lng, col), bb = ld1<F32>(lnb, col);
#pragma unroll
        for (int r = 0; r < 4; r++) {
            int row = strip * 16 + qd * 4 + r;
            float v = (acc[j][r] - mean[r]) * rstd[r] * gg + bb;
            size_t oi = hoff + (size_t)row * 512 + col;
            if constexpr (F32) ((float*)out)[oi] = v;
            else               ((bf16_t*)out)[oi] = (bf16_t)v;
        }
    }
}

extern "C" void kernel_launch(void* const* d_in, const int* in_sizes, int n_in,
                              void* d_out, int out_size, void* d_ws, size_t ws_size,
                              hipStream_t stream) {
    const void* H    = d_in[0];
    const void* Z    = d_in[1];
    const void* Whk  = d_in[2];
    const void* Whv  = d_in[3];
    const void* Wzk  = d_in[4];
    const void* Wzv  = d_in[5];
    const void* Wq   = d_in[6];
    const void* Wout = d_in[7];
    const void* lng  = d_in[8];
    const void* lnb  = d_in[9];

    bf16_t* WH = (bf16_t*)d_ws;        // [1024, 512] bf16
    bf16_t* WZ = WH + 1024 * 512;      // [1024, 512] bf16
    int* flag  = (int*)(WZ + 1024 * 512);

    k_detect<<<1, 64, 0, stream>>>(lng, flag);
    k_fusew<false><<<256, 256, 0, stream>>>(Whk, Whv, Wzk, Wzv, Wq, Wout, WH, WZ, flag);
    k_fusew<true ><<<256, 256, 0, stream>>>(Whk, Whv, Wzk, Wzv, Wq, Wout, WH, WZ, flag);
    k_batch<false><<<256, 1024, 0, stream>>>(H, Z, WH, WZ, lng, lnb, d_out, flag);
    k_batch<true ><<<256, 1024, 0, stream>>>(H, Z, WH, WZ, lng, lnb, d_out, flag);
}

// Round 4
// 277.706 us; speedup vs baseline: 2.4264x; 2.4264x over previous
//
#include <hip/hip_runtime.h>
#include <hip/hip_bf16.h>
#include <cstdint>
#include <cstddef>

typedef __bf16 bf16_t;
typedef __bf16 bf16x8 __attribute__((ext_vector_type(8)));
typedef __bf16 bf16x4 __attribute__((ext_vector_type(4)));
typedef float f32x4 __attribute__((ext_vector_type(4)));

#define MFMA16(a, b, c) __builtin_amdgcn_mfma_f32_16x16x32_bf16((a), (b), (c), 0, 0, 0)

// 8 contiguous f32 -> bf16x8
__device__ __forceinline__ bf16x8 ld8f(const float* p) {
    f32x4 a = *reinterpret_cast<const f32x4*>(p);
    f32x4 b = *reinterpret_cast<const f32x4*>(p + 4);
    bf16x8 r;
    r[0] = (bf16_t)a[0]; r[1] = (bf16_t)a[1]; r[2] = (bf16_t)a[2]; r[3] = (bf16_t)a[3];
    r[4] = (bf16_t)b[0]; r[5] = (bf16_t)b[1]; r[6] = (bf16_t)b[2]; r[7] = (bf16_t)b[3];
    return r;
}
__device__ __forceinline__ bf16x8 ldg8(const bf16_t* p) {
    return *reinterpret_cast<const bf16x8*>(p);
}

// ---------------------------------------------------------------------------
// K1: fused weights -> W bf16[1024][1024].  Row j = output dim (j<512 logit,
// j>=512 value); col = input dim (col<512 h-part, col>=512 z-part).
//  W[j,d]       = RS * sum_e Wq[e,j]        * Whk[e,d]
//  W[512+o,d]   =      sum_e Wout[o,e]      * Whv[e,d]
//  W[j,512+d]   = RS * sum_e Wq[1024+e,j]   * Wzk[e,d]
//  W[512+o,512+d]=     sum_e Wout[o,1024+e] * Wzv[e,d]
// ---------------------------------------------------------------------------
__global__ __launch_bounds__(256) void k_fusew(
    const float* __restrict__ Whk, const float* __restrict__ Whv,
    const float* __restrict__ Wzk, const float* __restrict__ Wzv,
    const float* __restrict__ Wq,  const float* __restrict__ Wout,
    bf16_t* __restrict__ W)
{
    __shared__ bf16_t LA[64][40];
    __shared__ bf16_t LB[64][40];
    const int tid = threadIdx.x;
    const int lane = tid & 63, wid = tid >> 6;
    const int L15 = lane & 15, qd = lane >> 4;
    const int quad = blockIdx.x & 3, tile = blockIdx.x >> 2;
    const int ti = (tile >> 3) * 64, tj = (tile & 7) * 64;
    const float RS = 0.04419417382415922f;  // 1/sqrt(512)

    const float* Lp; const float* Rp; int orow, ocol; float scale; int transL;
    switch (quad) {
        case 0:  Lp = Wq;           Rp = Whk; orow = 0;   ocol = 0;   scale = RS;  transL = 1; break;
        case 1:  Lp = Wout;         Rp = Whv; orow = 512; ocol = 0;   scale = 1.f; transL = 0; break;
        case 2:  Lp = Wq + 524288;  Rp = Wzk; orow = 0;   ocol = 512; scale = RS;  transL = 1; break;
        default: Lp = Wout + 1024;  Rp = Wzv; orow = 512; ocol = 512; scale = 1.f; transL = 0; break;
    }

    f32x4 acc[4];
#pragma unroll
    for (int t = 0; t < 4; t++) acc[t] = (f32x4){0.f, 0.f, 0.f, 0.f};

    for (int kc = 0; kc < 32; kc++) {
        const int k0 = kc * 32;
        __syncthreads();
        if (transL) {
            int k = tid >> 3, i0 = (tid & 7) * 8;
            bf16x8 v = ld8f(Lp + (size_t)(k0 + k) * 512 + ti + i0);
#pragma unroll
            for (int u = 0; u < 8; u++) LA[i0 + u][k] = v[u];
        } else {
            int i = tid >> 2, kk0 = (tid & 3) * 8;
            bf16x8 v = ld8f(Lp + (size_t)(ti + i) * 2048 + k0 + kk0);
            *reinterpret_cast<bf16x8*>(&LA[i][kk0]) = v;
        }
        {
            int k = tid >> 3, j0 = (tid & 7) * 8;
            bf16x8 v = ld8f(Rp + (size_t)(k0 + k) * 512 + tj + j0);
#pragma unroll
            for (int u = 0; u < 8; u++) LB[j0 + u][k] = v[u];
        }
        __syncthreads();
        bf16x8 af = *reinterpret_cast<bf16x8*>(&LA[wid * 16 + L15][qd * 8]);
#pragma unroll
        for (int t = 0; t < 4; t++) {
            bf16x8 bfr = *reinterpret_cast<bf16x8*>(&LB[t * 16 + L15][qd * 8]);
            acc[t] = MFMA16(af, bfr, acc[t]);
        }
    }
#pragma unroll
    for (int t = 0; t < 4; t++) {
        int col = ocol + tj + t * 16 + L15;
#pragma unroll
        for (int r = 0; r < 4; r++) {
            int row = orow + ti + wid * 16 + qd * 4 + r;
            W[(size_t)row * 1024 + col] = (bf16_t)(acc[t][r] * scale);
        }
    }
}

// ---------------------------------------------------------------------------
// K2: C[16384x1024] = [H|Z] (f32) x W^T (bf16).  128x128 tiles, BK=32.
//   nb<4: G half,  G[m*512 + j]                (bf16, row-major)
//   nb>=4: VV half, VT[n*32768 + dloc*64 + kl] (bf16, pre-transposed per batch)
// ---------------------------------------------------------------------------
__global__ __launch_bounds__(256) void k_gemm(
    const float* __restrict__ H, const float* __restrict__ Z,
    const bf16_t* __restrict__ W,
    bf16_t* __restrict__ G, bf16_t* __restrict__ VT)
{
    __shared__ bf16_t SA[128 * 32];
    __shared__ bf16_t SB[128 * 32];
    const int tid = threadIdx.x, lane = tid & 63, wid = tid >> 6;
    const int L15 = lane & 15, qd = lane >> 4;
    const int mb = blockIdx.x >> 3, nb = blockIdx.x & 7;
    const int m0 = mb * 128, n0 = nb * 128;
    const int wy = wid & 1, wx = wid >> 1;
    const int sr = tid >> 1, sc = (tid & 1) * 16;

    f32x4 acc[4][4];
#pragma unroll
    for (int mt = 0; mt < 4; mt++)
#pragma unroll
        for (int nt = 0; nt < 4; nt++) acc[mt][nt] = (f32x4){0.f, 0.f, 0.f, 0.f};

    for (int kc = 0; kc < 32; kc++) {
        const int k0 = kc * 32;
        const float* src = (kc < 16) ? H : Z;
        const int kk = (k0 & 511) + sc;
        __syncthreads();
        {   // A: rows m0+sr, 16 f32 -> bf16
            const float* pa = src + (size_t)(m0 + sr) * 512 + kk;
            bf16x8 v0 = ld8f(pa);
            bf16x8 v1 = ld8f(pa + 8);
            *reinterpret_cast<bf16x8*>(&SA[sr * 32 + sc]) = v0;
            *reinterpret_cast<bf16x8*>(&SA[sr * 32 + sc + 8]) = v1;
            // B: rows n0+sr of W
            const bf16_t* pb = W + (size_t)(n0 + sr) * 1024 + k0 + sc;
            *reinterpret_cast<bf16x8*>(&SB[sr * 32 + sc]) = ldg8(pb);
            *reinterpret_cast<bf16x8*>(&SB[sr * 32 + sc + 8]) = ldg8(pb + 8);
        }
        __syncthreads();
        bf16x8 af[4], bf[4];
#pragma unroll
        for (int mt = 0; mt < 4; mt++)
            af[mt] = *reinterpret_cast<bf16x8*>(&SA[(wy * 64 + mt * 16 + L15) * 32 + qd * 8]);
#pragma unroll
        for (int nt = 0; nt < 4; nt++)
            bf[nt] = *reinterpret_cast<bf16x8*>(&SB[(wx * 64 + nt * 16 + L15) * 32 + qd * 8]);
#pragma unroll
        for (int mt = 0; mt < 4; mt++)
#pragma unroll
            for (int nt = 0; nt < 4; nt++)
                acc[mt][nt] = MFMA16(af[mt], bf[nt], acc[mt][nt]);
    }

    if (nb < 4) {
#pragma unroll
        for (int mt = 0; mt < 4; mt++) {
            int mrow = m0 + wy * 64 + mt * 16 + qd * 4;
#pragma unroll
            for (int nt = 0; nt < 4; nt++) {
                int j = n0 + wx * 64 + nt * 16 + L15;
#pragma unroll
                for (int r = 0; r < 4; r++)
                    G[(size_t)(mrow + r) * 512 + j] = (bf16_t)acc[mt][nt][r];
            }
        }
    } else {
#pragma unroll
        for (int mt = 0; mt < 4; mt++) {
            int mrow = m0 + wy * 64 + mt * 16 + qd * 4;
            int n = mrow >> 6, kl = mrow & 63;
#pragma unroll
            for (int nt = 0; nt < 4; nt++) {
                int dloc = n0 - 512 + wx * 64 + nt * 16 + L15;
                bf16x4 pk;
#pragma unroll
                for (int r = 0; r < 4; r++) pk[r] = (bf16_t)acc[mt][nt][r];
                *reinterpret_cast<bf16x4*>(&VT[(size_t)n * 32768 + (size_t)dloc * 64 + kl]) = pk;
            }
        }
    }
}

// ---------------------------------------------------------------------------
// K3: per-batch attention + LN.  256 blocks x 512 threads (8 waves).
// logits[k,q] = sum_d G[k,d] h[q,d]; P = softmax_q; out = LN(P @ VV)
// wave = (strip = w&3 : 16 k-rows, half = w>>2 : q-half then d-half)
// ---------------------------------------------------------------------------
__global__ __launch_bounds__(512) void k_attn(
    const float* __restrict__ H,
    const bf16_t* __restrict__ G, const bf16_t* __restrict__ VT,
    const float* __restrict__ lng, const float* __restrict__ lnb,
    float* __restrict__ out)
{
    __shared__ float  Sl[64][72];
    __shared__ bf16_t Sp[64][72];
    __shared__ float  Rs[2][64];
    __shared__ float  Rq[2][64];
    const int n = blockIdx.x;
    const int tid = threadIdx.x, lane = tid & 63, w = tid >> 6;
    const int L15 = lane & 15, qd = lane >> 4;
    const int strip = w & 3, half = w >> 2;
    const bf16_t* Gb = G + (size_t)n * 32768;
    const bf16_t* Vb = VT + (size_t)n * 32768;
    const float*  Hb = H + (size_t)n * 32768;

    {   // logits
        f32x4 lg[2];
        lg[0] = (f32x4){0.f, 0.f, 0.f, 0.f};
        lg[1] = (f32x4){0.f, 0.f, 0.f, 0.f};
#pragma unroll 4
        for (int ks = 0; ks < 16; ks++) {
            bf16x8 a = ldg8(Gb + (size_t)(strip * 16 + L15) * 512 + ks * 32 + qd * 8);
#pragma unroll
            for (int qt = 0; qt < 2; qt++) {
                int q = half * 32 + qt * 16 + L15;
                bf16x8 b = ld8f(Hb + (size_t)q * 512 + ks * 32 + qd * 8);
                lg[qt] = MFMA16(a, b, lg[qt]);
            }
        }
#pragma unroll
        for (int qt = 0; qt < 2; qt++)
#pragma unroll
            for (int r = 0; r < 4; r++)
                Sl[strip * 16 + qd * 4 + r][half * 32 + qt * 16 + L15] = lg[qt][r];
    }
    __syncthreads();
    {   // softmax over q: 8 threads/row, 8 cols each
        int row = tid >> 3, c0 = (tid & 7) * 8;
        float4 v0 = *reinterpret_cast<float4*>(&Sl[row][c0]);
        float4 v1 = *reinterpret_cast<float4*>(&Sl[row][c0 + 4]);
        float mx = fmaxf(fmaxf(fmaxf(v0.x, v0.y), fmaxf(v0.z, v0.w)),
                         fmaxf(fmaxf(v1.x, v1.y), fmaxf(v1.z, v1.w)));
#pragma unroll
        for (int m = 1; m < 8; m <<= 1) mx = fmaxf(mx, __shfl_xor(mx, m));
        float e[8];
        e[0] = __expf(v0.x - mx); e[1] = __expf(v0.y - mx);
        e[2] = __expf(v0.z - mx); e[3] = __expf(v0.w - mx);
        e[4] = __expf(v1.x - mx); e[5] = __expf(v1.y - mx);
        e[6] = __expf(v1.z - mx); e[7] = __expf(v1.w - mx);
        float s = 0.f;
#pragma unroll
        for (int u = 0; u < 8; u++) s += e[u];
#pragma unroll
        for (int m = 1; m < 8; m <<= 1) s += __shfl_xor(s, m);
        float inv = 1.0f / s;
        bf16x8 p;
#pragma unroll
        for (int u = 0; u < 8; u++) p[u] = (bf16_t)(e[u] * inv);
        *reinterpret_cast<bf16x8*>(&Sp[row][c0]) = p;
    }
    __syncthreads();

    // PV: wave (strip, dhalf): rows strip*16.., cols dhalf*256 + dt*16+L15
    f32x4 acc[16];
#pragma unroll
    for (int dt = 0; dt < 16; dt++) acc[dt] = (f32x4){0.f, 0.f, 0.f, 0.f};
#pragma unroll
    for (int kq = 0; kq < 2; kq++) {
        bf16x8 ap = *reinterpret_cast<bf16x8*>(&Sp[strip * 16 + L15][kq * 32 + qd * 8]);
#pragma unroll
        for (int dt = 0; dt < 16; dt++) {
            int d = half * 256 + dt * 16 + L15;
            bf16x8 bv = ldg8(Vb + (size_t)d * 64 + kq * 32 + qd * 8);
            acc[dt] = MFMA16(ap, bv, acc[dt]);
        }
    }
    // LN partials over this wave's 256 cols
    float s4[4] = {0.f, 0.f, 0.f, 0.f}, ss4[4] = {0.f, 0.f, 0.f, 0.f};
#pragma unroll
    for (int dt = 0; dt < 16; dt++)
#pragma unroll
        for (int r = 0; r < 4; r++) { float x = acc[dt][r]; s4[r] += x; ss4[r] += x * x; }
#pragma unroll
    for (int m = 1; m < 16; m <<= 1)
#pragma unroll
        for (int r = 0; r < 4; r++) {
            s4[r]  += __shfl_xor(s4[r], m);
            ss4[r] += __shfl_xor(ss4[r], m);
        }
    if (L15 == 0)
#pragma unroll
        for (int r = 0; r < 4; r++) {
            int row = strip * 16 + qd * 4 + r;
            Rs[half][row] = s4[r];
            Rq[half][row] = ss4[r];
        }
    __syncthreads();
    float mean[4], rstd[4];
#pragma unroll
    for (int r = 0; r < 4; r++) {
        int row = strip * 16 + qd * 4 + r;
        float S = Rs[0][row] + Rs[1][row];
        float Q = Rq[0][row] + Rq[1][row];
        float mu = S * (1.f / 512.f);
        float var = Q * (1.f / 512.f) - mu * mu;
        mean[r] = mu;
        rstd[r] = rsqrtf(var + 1e-5f);
    }
    float* ob = out + (size_t)n * 32768;
#pragma unroll
    for (int dt = 0; dt < 16; dt++) {
        int col = half * 256 + dt * 16 + L15;
        float gg = lng[col], bb = lnb[col];
#pragma unroll
        for (int r = 0; r < 4; r++) {
            int row = strip * 16 + qd * 4 + r;
            ob[(size_t)row * 512 + col] = (acc[dt][r] - mean[r]) * rstd[r] * gg + bb;
        }
    }
}

// ---------------------------------------------------------------------------
// Fallback fused per-batch kernel (R3 structure, reads combined W) — used only
// if ws_size is too small for the split pipeline.
// ---------------------------------------------------------------------------
__global__ __launch_bounds__(1024) void k_batch_fb(
    const float* __restrict__ H, const float* __restrict__ Z,
    const bf16_t* __restrict__ W,
    const float* __restrict__ lng, const float* __restrict__ lnb,
    float* __restrict__ out)
{
    __shared__ __align__(16) char lds_raw[48128];
    bf16_t* lds_bf = (bf16_t*)lds_raw;
    float*  lds_f  = (float*)lds_raw;
    bf16_t* Gbuf = lds_bf;
    float*  Sl   = lds_f;
    bf16_t* VTl  = lds_bf;
    bf16_t* Sp   = lds_bf + 18432;
    float*  Rs   = lds_f + 11520;
    float*  Rq   = lds_f + 11776;

    const int n = blockIdx.x;
    const int tid = threadIdx.x, lane = tid & 63, w = tid >> 6;
    const int L15 = lane & 15, qd = lane >> 4;
    const int strip = w & 3, grp = w >> 2;
    const float* Hb = H + (size_t)n * 32768;
    const float* Zb = Z + (size_t)n * 32768;

    f32x4 a1 = (f32x4){0.f, 0.f, 0.f, 0.f};
    for (int hf = 0; hf < 2; hf++) {
        f32x4 ga[4];
#pragma unroll
        for (int mt = 0; mt < 4; mt++) ga[mt] = (f32x4){0.f, 0.f, 0.f, 0.f};
        const bf16_t* wrow = W + (size_t)(hf * 256 + w * 16 + L15) * 1024;
#pragma unroll 4
        for (int kc = 0; kc < 16; kc++) {
            const int ko = kc * 32 + qd * 8;
            bf16x8 bh = ldg8(wrow + ko);
            bf16x8 bz = ldg8(wrow + 512 + ko);
#pragma unroll
            for (int mt = 0; mt < 4; mt++) {
                bf16x8 ah = ld8f(Hb + (size_t)(mt * 16 + L15) * 512 + ko);
                bf16x8 az = ld8f(Zb + (size_t)(mt * 16 + L15) * 512 + ko);
                ga[mt] = MFMA16(ah, bh, ga[mt]);
                ga[mt] = MFMA16(az, bz, ga[mt]);
            }
        }
        __syncthreads();
#pragma unroll
        for (int mt = 0; mt < 4; mt++)
#pragma unroll
            for (int r = 0; r < 4; r++)
                Gbuf[(size_t)(mt * 16 + qd * 4 + r) * 264 + w * 16 + L15] = (bf16_t)ga[mt][r];
        __syncthreads();
#pragma unroll
        for (int kcf = 0; kcf < 8; kcf++) {
            bf16x8 af = *reinterpret_cast<bf16x8*>(
                &Gbuf[(size_t)(strip * 16 + L15) * 264 + kcf * 32 + qd * 8]);
            bf16x8 bq = ld8f(Hb + (size_t)(grp * 16 + L15) * 512 + hf * 256 + kcf * 32 + qd * 8);
            a1 = MFMA16(af, bq, a1);
        }
    }
    __syncthreads();
#pragma unroll
    for (int r = 0; r < 4; r++)
        Sl[(size_t)(strip * 16 + qd * 4 + r) * 64 + grp * 16 + L15] = a1[r];
    __syncthreads();
    {
        int row = tid >> 4, c0 = (tid & 15) * 4;
        float4 v = *reinterpret_cast<float4*>(&Sl[(size_t)row * 64 + c0]);
        float mx = fmaxf(fmaxf(v.x, v.y), fmaxf(v.z, v.w));
#pragma unroll
        for (int m = 1; m < 16; m <<= 1) mx = fmaxf(mx, __shfl_xor(mx, m));
        float e0 = __expf(v.x - mx), e1 = __expf(v.y - mx);
        float e2 = __expf(v.z - mx), e3 = __expf(v.w - mx);
        float s = e0 + e1 + e2 + e3;
#pragma unroll
        for (int m = 1; m < 16; m <<= 1) s += __shfl_xor(s, m);
        float inv = 1.0f / s;
        bf16x4 p;
        p[0] = (bf16_t)(e0 * inv); p[1] = (bf16_t)(e1 * inv);
        p[2] = (bf16_t)(e2 * inv); p[3] = (bf16_t)(e3 * inv);
        *reinterpret_cast<bf16x4*>(&Sp[(size_t)row * 72 + c0]) = p;
    }
    __syncthreads();

    f32x4 acc[8];
#pragma unroll
    for (int j = 0; j < 8; j++) acc[j] = (f32x4){0.f, 0.f, 0.f, 0.f};
    for (int hf2 = 0; hf2 < 2; hf2++) {
        f32x4 va[4];
#pragma unroll
        for (int mt = 0; mt < 4; mt++) va[mt] = (f32x4){0.f, 0.f, 0.f, 0.f};
        const bf16_t* wrow = W + (size_t)(512 + hf2 * 256 + w * 16 + L15) * 1024;
#pragma unroll 4
        for (int kc = 0; kc < 16; kc++) {
            const int ko = kc * 32 + qd * 8;
            bf16x8 bh = ldg8(wrow + ko);
            bf16x8 bz = ldg8(wrow + 512 + ko);
#pragma unroll
            for (int mt = 0; mt < 4; mt++) {
                bf16x8 ah = ld8f(Hb + (size_t)(mt * 16 + L15) * 512 + ko);
                bf16x8 az = ld8f(Zb + (size_t)(mt * 16 + L15) * 512 + ko);
                va[mt] = MFMA16(ah, bh, va[mt]);
                va[mt] = MFMA16(az, bz, va[mt]);
            }
        }
#pragma unroll
        for (int mt = 0; mt < 4; mt++) {
            bf16x4 pk;
#pragma unroll
            for (int r = 0; r < 4; r++) pk[r] = (bf16_t)va[mt][r];
            *reinterpret_cast<bf16x4*>(&VTl[(size_t)(w * 16 + L15) * 72 + mt * 16 + qd * 4]) = pk;
        }
        __syncthreads();
#pragma unroll
        for (int kcq = 0; kcq < 2; kcq++) {
            bf16x8 ap = *reinterpret_cast<bf16x8*>(
                &Sp[(size_t)(strip * 16 + L15) * 72 + kcq * 32 + qd * 8]);
#pragma unroll
            for (int dt = 0; dt < 4; dt++) {
                bf16x8 bv = *reinterpret_cast<bf16x8*>(
                    &VTl[(size_t)(grp * 64 + dt * 16 + L15) * 72 + kcq * 32 + qd * 8]);
                acc[hf2 * 4 + dt] = MFMA16(ap, bv, acc[hf2 * 4 + dt]);
            }
        }
        __syncthreads();
    }
    float s4[4] = {0.f, 0.f, 0.f, 0.f}, ss4[4] = {0.f, 0.f, 0.f, 0.f};
#pragma unroll
    for (int j = 0; j < 8; j++)
#pragma unroll
        for (int r = 0; r < 4; r++) { float x = acc[j][r]; s4[r] += x; ss4[r] += x * x; }
#pragma unroll
    for (int m = 1; m < 16; m <<= 1)
#pragma unroll
        for (int r = 0; r < 4; r++) {
            s4[r]  += __shfl_xor(s4[r], m);
            ss4[r] += __shfl_xor(ss4[r], m);
        }
    if (L15 == 0)
#pragma unroll
        for (int r = 0; r < 4; r++) {
            int row = strip * 16 + qd * 4 + r;
            Rs[grp * 64 + row] = s4[r];
            Rq[grp * 64 + row] = ss4[r];
        }
    __syncthreads();
    float mean[4], rstd[4];
#pragma unroll
    for (int r = 0; r < 4; r++) {
        int row = strip * 16 + qd * 4 + r;
        float S = Rs[row] + Rs[64 + row] + Rs[128 + row] + Rs[192 + row];
        float Q = Rq[row] + Rq[64 + row] + Rq[128 + row] + Rq[192 + row];
        float mu = S * (1.f / 512.f);
        float var = Q * (1.f / 512.f) - mu * mu;
        mean[r] = mu;
        rstd[r] = rsqrtf(var + 1e-5f);
    }
#pragma unroll
    for (int j = 0; j < 8; j++) {
        int col = (j >> 2) * 256 + grp * 64 + (j & 3) * 16 + L15;
        float gg = lng[col], bb = lnb[col];
#pragma unroll
        for (int r = 0; r < 4; r++) {
            int row = strip * 16 + qd * 4 + r;
            out[(size_t)n * 32768 + (size_t)row * 512 + col] =
                (acc[j][r] - mean[r]) * rstd[r] * gg + bb;
        }
    }
}

extern "C" void kernel_launch(void* const* d_in, const int* in_sizes, int n_in,
                              void* d_out, int out_size, void* d_ws, size_t ws_size,
                              hipStream_t stream) {
    const float* H    = (const float*)d_in[0];
    const float* Z    = (const float*)d_in[1];
    const float* Whk  = (const float*)d_in[2];
    const float* Whv  = (const float*)d_in[3];
    const float* Wzk  = (const float*)d_in[4];
    const float* Wzv  = (const float*)d_in[5];
    const float* Wq   = (const float*)d_in[6];
    const float* Wout = (const float*)d_in[7];
    const float* lng  = (const float*)d_in[8];
    const float* lnb  = (const float*)d_in[9];

    bf16_t* W  = (bf16_t*)d_ws;            // [1024][1024]   2 MiB
    bf16_t* G  = W + 1024 * 1024;          // [16384][512]  16 MiB
    bf16_t* VT = G + 16384 * 512;          // [256][512][64] 16 MiB
    const size_t need = (size_t)(1024 * 1024 + 16384 * 512 + 256 * 512 * 64) * 2;

    k_fusew<<<256, 256, 0, stream>>>(Whk, Whv, Wzk, Wzv, Wq, Wout, W);
    if (ws_size >= need) {
        k_gemm<<<1024, 256, 0, stream>>>(H, Z, W, G, VT);
        k_attn<<<256, 512, 0, stream>>>(H, G, VT, lng, lnb, (float*)d_out);
    } else {
        k_batch_fb<<<256, 1024, 0, stream>>>(H, Z, W, lng, lnb, (float*)d_out);
    }
}